// Round 8
// baseline (259.119 us; speedup 1.0000x reference)
//
#include <hip/hip_runtime.h>
#include <hip/hip_bf16.h>

#define IMG 28
#define KX 784             // true K = 28*28
#define KT 25              // k-tiles of 32 -> K padded to 800
#define NT 13              // n-tiles of 16 -> N padded to 208
#define NH 200
#define NOUT 10
#define WV 4               // waves per block
#define MW 16              // images per wave (one 16-row m-frag)
#define HSTRIDE 212        // fp32 elems per LDS h row (212%32=20 -> 0 conflicts, measured r5)
#define NPLANES (KT * NT)  // 325 B-fragments

typedef __attribute__((ext_vector_type(8))) short bf16x8;
typedef __attribute__((ext_vector_type(4))) float f32x4;

static __device__ __forceinline__ unsigned short bf16_bits(float v) {
    __hip_bfloat16 b = __float2bfloat16(v);
    return *(unsigned short*)&b;
}

static __device__ __forceinline__ bf16x8 cvt8(float4 a, float4 b) {
    bf16x8 r;
    r[0] = (short)bf16_bits(a.x); r[1] = (short)bf16_bits(a.y);
    r[2] = (short)bf16_bits(a.z); r[3] = (short)bf16_bits(a.w);
    r[4] = (short)bf16_bits(b.x); r[5] = (short)bf16_bits(b.y);
    r[6] = (short)bf16_bits(b.z); r[7] = (short)bf16_bits(b.w);
    return r;
}

// --- build W_eff = w0 composed with conv, packed in MFMA fragment order ---
// Plane-major by kt: per-kt B reads are one contiguous 13 KB stream.
// Bf[((kt*NT + nt)*64 + L)*8 + j] = W_eff[nt*16+(L&15)][kt*32+(L>>4)*8+j], 0-padded.
__global__ void build_weff(const float* __restrict__ w0, const float* __restrict__ cw,
                           __hip_bfloat16* __restrict__ Bf) {
    int idx = blockIdx.x * blockDim.x + threadIdx.x;
    if (idx >= NPLANES * 512) return;
    int j = idx & 7, L = (idx >> 3) & 63;
    int plane = idx >> 9;                  // 0..324
    int nt = plane % NT, kt = plane / NT;
    int n = nt * 16 + (L & 15);
    int k = kt * 32 + ((L >> 4) << 3) + j;
    float acc = 0.f;
    if (n < NH && k < KX) {
        int u = k / IMG, v = k - u * IMG;
#pragma unroll
        for (int i = 0; i < 3; ++i) {
#pragma unroll
            for (int jj = 0; jj < 3; ++jj) {
                int r = u - i, c = v - jj;
                if (r >= 0 && r < 26 && c >= 0 && c < 26)
                    acc += cw[i * 3 + jj] * w0[n * 676 + r * 26 + c];
            }
        }
    }
    Bf[idx] = __float2bfloat16(acc);
}

// Wave-autonomous fused kernel, r0-idiomatic codegen:
//  - kt loop unrolled 25x; A-ring a0[4]/a1[4] indexed [kt&3] (r0's proven p-ring idiom);
//  - B as flat b[13], refilled per-kt by unrolled n (r0's proven pattern);
//  - per kt: 2 HBM A-loads (16 full 128B lines), 13 L2 B-loads, 13 MFMAs.
// FIFO discipline: B(kt+1) issued BEFORE A(kt+4) each iter; A consumed at
// 4-iter lead (~1200 cyc > 900 cyc HBM) -> steady state never stalls on HBM.
// Loads are NEVER drained by a barrier: the per-kt s_barrier only paces the
// block's 4 waves onto the same B plane for L1 reuse.
// (256,2): 256-VGPR cap (demand ~155, no spill), 2 blocks/CU, all 512 blocks
// resident simultaneously (512 = 256 CUs x 2).
__global__ __launch_bounds__(256, 2) void gemm_fused_kernel(
    const float* __restrict__ x,            // [32768, 784]
    const __hip_bfloat16* __restrict__ Bf,  // [kt][nt]-packed W_eff
    const float* __restrict__ b0,           // [200]
    const float* __restrict__ w1,           // [10, 200]
    const float* __restrict__ b1,           // [10]
    float* __restrict__ out)                // [32768, 10]
{
    __shared__ __align__(16) float H[WV][MW][HSTRIDE];   // 54,272 B, wave-private rows

    const int tid  = threadIdx.x;
    const int wave = tid >> 6;
    const int L    = tid & 63;
    const int lm   = L & 15;
    const int q    = L >> 4;
    const int img0 = (blockIdx.x * WV + wave) * MW;

    // lane's A base: row img0+lm, k-offset q*8 (A-frag: row=L&15, k=(L>>4)*8+j)
    const float* xl = x + (size_t)(img0 + lm) * KX + q * 8;
    const bf16x8* bb = (const bf16x8*)Bf + L;

    f32x4 acc[NT];
#pragma unroll
    for (int n = 0; n < NT; ++n) acc[n] = (f32x4){0.f, 0.f, 0.f, 0.f};

    bf16x8 b[NT];          // plane kt resident (52 VGPR)
    float4 a0[4], a1[4];   // A ring, 4 kt deep (32 VGPR), slot = kt&3

    // ---- prologue: issue A(0..3) and B plane 0 ----
#pragma unroll
    for (int d = 0; d < 4; ++d) {
        a0[d] = *(const float4*)(xl + d * 32);
        a1[d] = *(const float4*)(xl + d * 32 + 4);
    }
#pragma unroll
    for (int n = 0; n < NT; ++n) b[n] = bb[n * 64];
    __builtin_amdgcn_sched_barrier(0);

    // ---- main loop ----
#pragma unroll
    for (int kt = 0; kt < KT; ++kt) {
        const int slot = kt & 3;
        // convert A(kt): waits only its own 2 loads, issued 4 iterations ago
        bf16x8 a = cvt8(a0[slot], a1[slot]);
        __builtin_amdgcn_s_barrier();          // pace 4 waves onto same B plane (L1 reuse)
#pragma unroll
        for (int n = 0; n < NT; ++n) {
            bf16x8 cur = b[n];
            if (kt + 1 < KT) b[n] = bb[((kt + 1) * NT + n) * 64];
            acc[n] = __builtin_amdgcn_mfma_f32_16x16x32_bf16(a, cur, acc[n], 0, 0, 0);
        }
        // refill A-ring slot with kt+4, AFTER the B issues (clean FIFO)
        if (kt + 4 < KT) {
            const float* p = xl + (kt + 4) * 32;
            if (kt + 4 == KT - 1) {
                // kt=24 covers cols 768..799; q>=2 lanes are K-pad (784..799)
                float4 z = {0.f, 0.f, 0.f, 0.f};
                if (q < 2) {
                    a0[slot] = *(const float4*)(p);
                    a1[slot] = *(const float4*)(p + 4);
                } else {
                    a0[slot] = z;
                    a1[slot] = z;
                }
            } else {
                a0[slot] = *(const float4*)(p);
                a1[slot] = *(const float4*)(p + 4);
            }
        }
        __builtin_amdgcn_sched_barrier(0);     // pin per-iter pipeline shape
    }

    // ---- epilogue: h = relu(acc + b0) -> wave-private LDS rows ----
#pragma unroll
    for (int n = 0; n < NT; ++n) {
        int col = n * 16 + lm;
        if (col < NH) {
            float bv = b0[col];
#pragma unroll
            for (int r = 0; r < 4; ++r) {
                float v = acc[n][r] + bv;
                H[wave][q * 4 + r][col] = v > 0.f ? v : 0.f;
            }
        }
    }
    // no barrier: H rows are wave-private; compiler's lgkmcnt orders write->read

    // ---- FC1: lane (lm,q) -> img=img0+lm, j in {q, q+4, q+8} ----
    const float* Hrow = &H[wave][lm][0];
    float fj0 = 0.f, fj1 = 0.f, fj2 = 0.f;
    const bool j2ok = (q < 2);      // q+8 < 10
#pragma unroll
    for (int c = 0; c < NH / 4; ++c) {
        float4 h4 = *(const float4*)(Hrow + c * 4);
        float4 w40 = *(const float4*)(w1 + q * NH + c * 4);
        float4 w41 = *(const float4*)(w1 + (q + 4) * NH + c * 4);
        fj0 += h4.x * w40.x + h4.y * w40.y + h4.z * w40.z + h4.w * w40.w;
        fj1 += h4.x * w41.x + h4.y * w41.y + h4.z * w41.z + h4.w * w41.w;
        if (j2ok) {
            float4 w42 = *(const float4*)(w1 + (q + 8) * NH + c * 4);
            fj2 += h4.x * w42.x + h4.y * w42.y + h4.z * w42.z + h4.w * w42.w;
        }
    }
    float* orow = out + (size_t)(img0 + lm) * NOUT;
    orow[q]     = fj0 + b1[q];
    orow[q + 4] = fj1 + b1[q + 4];
    if (j2ok) orow[q + 8] = fj2 + b1[q + 8];
}

extern "C" void kernel_launch(void* const* d_in, const int* in_sizes, int n_in,
                              void* d_out, int out_size, void* d_ws, size_t ws_size,
                              hipStream_t stream) {
    const float* x   = (const float*)d_in[0];
    const float* cw  = (const float*)d_in[1];
    const float* w0  = (const float*)d_in[2];
    const float* b0  = (const float*)d_in[3];
    const float* w1  = (const float*)d_in[4];
    const float* b1  = (const float*)d_in[5];
    float* out = (float*)d_out;

    __hip_bfloat16* Bf = (__hip_bfloat16*)d_ws;  // 325*512*2 = 332,800 B

    const int pack_elems = NPLANES * 512;
    build_weff<<<(pack_elems + 255) / 256, 256, 0, stream>>>(w0, cw, Bf);

    // 32768 images / (4 waves * 16 images) = 512 blocks = 2/CU, all resident
    gemm_fused_kernel<<<32768 / (WV * MW), 256, 0, stream>>>(x, Bf, b0, w1, b1, out);
}

// Round 9
// 189.724 us; speedup vs baseline: 1.3658x; 1.3658x over previous
//
#include <hip/hip_runtime.h>
#include <hip/hip_bf16.h>

#define KX 784             // true K = 28*28
#define KT 25              // k-tiles of 32 -> K padded to 800
#define NT 13              // n-tiles of 16 -> N padded to 208; waves {2,2,2,2,2,1,1,1}
#define NH 200
#define NOUT 10
#define MT 32              // images per block
#define CHK 5              // k-tiles per chunk
#define NCH 5              // chunks
#define HSTRIDE 212        // fp32 elems per LDS h row (0 bank conflicts, measured r5)

// LDS map (bytes): fp32 ring 3 x 5 panels x 4096 = 61,440
//                  bf16 A    25 panels x 2048    = 51,200  @ 61,440
//                  H         32 x 212 x 4        = 27,136  @ 112,640   total 139,776
#define SLOT_BYTES (CHK * 4096)
#define LDS_BF16   61440
#define LDS_H      112640
#define LDS_TOTAL  139776

typedef __attribute__((ext_vector_type(8))) short bf16x8;
typedef __attribute__((ext_vector_type(4))) float f32x4;
typedef __attribute__((ext_vector_type(4))) short s16x4;
typedef const __attribute__((address_space(1))) void gvoid;
typedef __attribute__((address_space(3))) void svoid;

static __device__ __forceinline__ unsigned short bf16_bits(float v) {
    __hip_bfloat16 b = __float2bfloat16(v);
    return *(unsigned short*)&b;
}

// --- build W_eff = w0 composed with conv, packed in MFMA fragment order ---
// r0 layout: Bf[nt][kt][lane][j] = W_eff[nt*16+(lane&15)][kt*32+(lane>>4)*8+j]
__global__ void build_weff(const float* __restrict__ w0, const float* __restrict__ cw,
                           __hip_bfloat16* __restrict__ Bf) {
    int idx = blockIdx.x * blockDim.x + threadIdx.x;
    if (idx >= NT * KT * 512) return;
    int j = idx & 7, L = (idx >> 3) & 63, kt = (idx >> 9) % KT, nt = idx / (KT * 512);
    int n = nt * 16 + (L & 15);
    int k = kt * 32 + ((L >> 4) << 3) + j;
    float acc = 0.f;
    if (n < NH && k < KX) {
        int u = k / 28, v = k - u * 28;
#pragma unroll
        for (int i = 0; i < 3; ++i)
#pragma unroll
            for (int jj = 0; jj < 3; ++jj) {
                int r = u - i, c = v - jj;
                if (r >= 0 && r < 26 && c >= 0 && c < 26)
                    acc += cw[i * 3 + jj] * w0[n * 676 + r * 26 + c];
            }
    }
    Bf[idx] = __float2bfloat16(acc);
}

// stage chunk c (waves 0-3 only): 5 panels, 1 global_load_lds per panel per wave.
// Panel (c,j) holds f32 cols (5c+j)*32..+31 of all 32 rows: [row 0..31][col4 0..7].
// LDS dest = wave-uniform base + lane*16 (HW rule); source addr is per-lane.
// Cols >783 clamp to 195 (garbage, never read: compute zero-substitutes kt=24,q>=2).
static __device__ __forceinline__ void stage_chunk(
    char* lds, const float4* __restrict__ xb4, int c, int tid)
{
    const int row = tid >> 3, col4 = tid & 7;
    char* base = lds + (c % 3) * SLOT_BYTES + ((tid >> 6) << 10);
#pragma unroll
    for (int j = 0; j < CHK; ++j) {
        int g4 = (c * CHK + j) * 8 + col4;
        const float4* src = xb4 + row * 196 + (g4 > 195 ? 195 : g4);
        __builtin_amdgcn_global_load_lds((gvoid*)src, (svoid*)(base + j * 4096), 16, 0, 0);
    }
}

// cvt chunk c: fp32 slot -> write-once bf16 region, all 512 threads.
// bf16 frag layout: panel*2048 + row*64 + (fragq ^ (row&3))*16 + half*8  (XOR-swizzle).
static __device__ __forceinline__ void cvt_chunk(char* lds, int c, int tid) {
    const float4* f32p = (const float4*)(lds + (c % 3) * SLOT_BYTES);
#pragma unroll
    for (int t = 0; t < 3; ++t) {
        if (t < 2 || tid < 256) {
            int e = tid + t * 512;                    // 0..1279
            float4 v = f32p[e];
            int j = e >> 8, s = e & 255;
            int row = s >> 3, col4 = s & 7;
            char* dst = lds + LDS_BF16 + (c * CHK + j) * 2048 + row * 64
                      + (((col4 >> 1) ^ (row & 3)) << 4) + ((col4 & 1) << 3);
            s16x4 p;
            p.x = (short)bf16_bits(v.x);
            p.y = (short)bf16_bits(v.y);
            p.z = (short)bf16_bits(v.z);
            p.w = (short)bf16_bits(v.w);
            *(s16x4*)dst = p;
        }
    }
}

// main pipeline: per step c = [vmcnt(lit) | bar | cvt(c) | bar | compute(c) | stage(c+2)]
template <int NTN, bool STAGER>
static __device__ __forceinline__ void pipe(
    char* lds, const float4* __restrict__ xb4, const bf16x8* __restrict__ bb,
    int tid, int lm, int q, bf16x8 p0[4], bf16x8 p1[4], f32x4 acc[2][2])
{
    const char* A0 = lds + LDS_BF16 + lm * 64 + ((q ^ (lm & 3)) << 4);
    const char* A1 = A0 + 16 * 64;
#pragma unroll
    for (int c = 0; c < NCH; ++c) {
        if (STAGER) {
            // exact FIFO: ensures stage(c) retired; stage(c+1) + B-prefetches in flight
            if (c == 0)      asm volatile("s_waitcnt vmcnt(5)" ::: "memory");
            else if (c == 4) asm volatile("s_waitcnt vmcnt(10)" ::: "memory");
            else             asm volatile("s_waitcnt vmcnt(15)" ::: "memory");
            __builtin_amdgcn_sched_barrier(0);
        }
        __builtin_amdgcn_s_barrier();            // stage(c) visible to all waves
        cvt_chunk(lds, c, tid);
        asm volatile("s_waitcnt lgkmcnt(0)" ::: "memory");
        __builtin_amdgcn_s_barrier();            // bf16(c) visible
#pragma unroll
        for (int k = 0; k < CHK; ++k) {
            const int kt = c * CHK + k;
            const int slot = kt & 3;
            bf16x8 b0v = p0[slot];
            bf16x8 b1v = p1[slot];
            if (kt + 4 < KT) {                   // B refill: L2 stream, distance 4
                p0[slot] = bb[(kt + 4) * 64];
                if (NTN == 2) p1[slot] = bb[(KT + kt + 4) * 64];
            }
            bf16x8 a0f = *(const bf16x8*)(A0 + kt * 2048);
            bf16x8 a1f = *(const bf16x8*)(A1 + kt * 2048);
            if (kt == KT - 1 && q >= 2) {        // K-pad cols 784..799: zero-substitute
                a0f = (bf16x8)(short)0;
                a1f = (bf16x8)(short)0;
            }
            acc[0][0] = __builtin_amdgcn_mfma_f32_16x16x32_bf16(a0f, b0v, acc[0][0], 0, 0, 0);
            acc[1][0] = __builtin_amdgcn_mfma_f32_16x16x32_bf16(a1f, b0v, acc[1][0], 0, 0, 0);
            if (NTN == 2) {
                acc[0][1] = __builtin_amdgcn_mfma_f32_16x16x32_bf16(a0f, b1v, acc[0][1], 0, 0, 0);
                acc[1][1] = __builtin_amdgcn_mfma_f32_16x16x32_bf16(a1f, b1v, acc[1][1], 0, 0, 0);
            }
        }
        if (STAGER && c + 2 < NCH) {             // AFTER refills: clean FIFO order
            stage_chunk(lds, xb4, c + 2, tid);
            __builtin_amdgcn_sched_barrier(0);
        }
    }
}

// (512,1): 1 block/CU (139.8 KB LDS), full register budget -> no spill possible
// on the staging path (it never touches VGPRs).
__global__ __launch_bounds__(512, 1) void gemm_fused_kernel(
    const float* __restrict__ x,            // [32768, 784]
    const __hip_bfloat16* __restrict__ Bf,  // fragment-packed W_eff
    const float* __restrict__ b0,           // [200]
    const float* __restrict__ w1,           // [10, 200]
    const float* __restrict__ b1,           // [10]
    float* __restrict__ out)                // [32768, 10]
{
    __shared__ __align__(16) char lds[LDS_TOTAL];

    const int tid  = threadIdx.x;
    const int wave = tid >> 6;
    const int L    = tid & 63;
    const int lm   = L & 15;
    const int q    = L >> 4;
    const int img0 = blockIdx.x * MT;
    const float4* xb4 = (const float4*)x + (size_t)img0 * 196;

    // n-tile ownership: waves {2,2,2,2,2,1,1,1}; waves 0-3 also stage
    const int ntbase = (wave < 5) ? wave * 2 : 10 + (wave - 5);
    const int ntn    = (wave < 5) ? 2 : 1;
    const bf16x8* bb = (const bf16x8*)Bf + (size_t)ntbase * KT * 64 + L;

    // prologue FIFO order: B preloads FIRST (so p-uses never drain stages), then stages
    bf16x8 p0[4], p1[4];
#pragma unroll
    for (int d = 0; d < 4; ++d) {
        p0[d] = bb[d * 64];
        p1[d] = (ntn == 2) ? bb[(KT + d) * 64] : p0[d];
    }
    if (wave < 4) {
        stage_chunk(lds, xb4, 0, tid);
        stage_chunk(lds, xb4, 1, tid);
        __builtin_amdgcn_sched_barrier(0);
    }

    f32x4 acc[2][2];
#pragma unroll
    for (int m = 0; m < 2; ++m)
#pragma unroll
        for (int t = 0; t < 2; ++t) acc[m][t] = (f32x4){0.f, 0.f, 0.f, 0.f};

    if (wave < 4)      pipe<2, true >(lds, xb4, bb, tid, lm, q, p0, p1, acc);
    else if (wave == 4) pipe<2, false>(lds, xb4, bb, tid, lm, q, p0, p1, acc);
    else                pipe<1, false>(lds, xb4, bb, tid, lm, q, p0, p1, acc);

    // epilogue: h = relu(acc + b0) -> H
    float* H = (float*)(lds + LDS_H);
#pragma unroll
    for (int t = 0; t < 2; ++t) {
        if (t < ntn) {
            int n = (ntbase + t) * 16 + lm;
            if (n < NH) {
                float bv = b0[n];
#pragma unroll
                for (int m = 0; m < 2; ++m)
#pragma unroll
                    for (int r = 0; r < 4; ++r) {
                        int mm = m * 16 + q * 4 + r;
                        float v = acc[m][t][r] + bv;
                        H[mm * HSTRIDE + n] = v > 0.f ? v : 0.f;
                    }
            }
        }
    }
    asm volatile("s_waitcnt lgkmcnt(0)" ::: "memory");
    __builtin_amdgcn_s_barrier();

    // FC1: out = h @ w1.T + b1 (fp32 VALU, 320 results/block)
    if (tid < MT * NOUT) {
        int i = tid / NOUT;
        int j = tid - i * NOUT;
        const float4* hrow = (const float4*)(H + i * HSTRIDE);
        const float4* wrow = (const float4*)(w1 + j * NH);
        float s = b1[j];
        float4 accv = {0.f, 0.f, 0.f, 0.f};
#pragma unroll 10
        for (int n = 0; n < NH / 4; ++n) {
            float4 h4 = hrow[n];
            float4 w4 = wrow[n];
            accv.x += h4.x * w4.x;
            accv.y += h4.y * w4.y;
            accv.z += h4.z * w4.z;
            accv.w += h4.w * w4.w;
        }
        s += (accv.x + accv.y) + (accv.z + accv.w);
        out[(size_t)(img0 + i) * NOUT + j] = s;
    }
}

extern "C" void kernel_launch(void* const* d_in, const int* in_sizes, int n_in,
                              void* d_out, int out_size, void* d_ws, size_t ws_size,
                              hipStream_t stream) {
    const float* x   = (const float*)d_in[0];
    const float* cw  = (const float*)d_in[1];
    const float* w0  = (const float*)d_in[2];
    const float* b0  = (const float*)d_in[3];
    const float* w1  = (const float*)d_in[4];
    const float* b1  = (const float*)d_in[5];
    float* out = (float*)d_out;

    __hip_bfloat16* Bf = (__hip_bfloat16*)d_ws;  // 13*25*512*2 = 332,800 B

    const int pack_elems = NT * KT * 512;
    build_weff<<<(pack_elems + 255) / 256, 256, 0, stream>>>(w0, cw, Bf);

    gemm_fused_kernel<<<32768 / MT, 512, 0, stream>>>(x, Bf, b0, w1, b1, out);
}